// Round 8
// baseline (94.982 us; speedup 1.0000x reference)
//
#include <hip/hip_runtime.h>
#include <math.h>

#define IR_LEN  2000
#define PFRAME  80
#define NFRAMES 300
#define NBATCH  2
#define NROWS   (NBATCH*NFRAMES)     // 600
#define T_TOTAL (NFRAMES*PFRAME)     // 24000
#define NCOEF   25
#define TWO_PI  6.283185307179586f
#define GS      68                   // G row stride in floats
#define XWN     2160                 // logical x-window floats per block
#define XWPAD   2432                 // physical (4-float pad per 32)

#define XPHYS(B) ((B) + (((B) >> 5) << 2))

__device__ __forceinline__ void fsincos(float a, float* s, float* c) {
    *s = __sinf(a); *c = __cosf(a);
}

// ---------------------------------------------------------------------------
// R24 = R23 (stagger + async-x, ~38-39 us / 86.3 bench) + ONE coupled change:
// radix-split S1 (32-pt a2-DFT -> 4x8) + compacted E storage.
//   Evidence: per-block wall ~4x pure issue; S1 is both the top VALU phase
//   (2.4k insts/thread on 144 thr) AND top LDS consumer (384 b128 reads,
//   only 9 unique addrs/inst = broadcast-wasted width).
//   S1a: P[r][d4][b] = sum_q E[1024q+128r+b] * i^(d4*q)  (q=0..3, trivial
//        twiddles -> pure adds; reads each E elem ONCE, full-width loads)
//   S1b: proven S1 loop verbatim with a2->r (8 iters) reading P (d4-plane),
//        identical rotator/butterfly/twiddle/store.
//   E compaction: S1 only reads f%128 in [0,36)u[64,100) -> store E at
//   stride 72 (live cols), skip dead stores/mirrors (E writes halve).
//   LDS: SH[9216] (E|P / G / hU|red union) + xws + csh = 46.7 KB -> still
//   3 blocks/CU.
// ---------------------------------------------------------------------------
__global__ __launch_bounds__(256) void minphase_fir_fused(
        const float* __restrict__ mc, const float* __restrict__ x,
        float* __restrict__ y) {
    __shared__ __align__(16) float SH[9216];   // 36.9 KB union
    __shared__ __align__(16) float xws[XWPAD]; // 9.7 KB padded x window
    __shared__ float csh[NCOEF];
    float* const Ecr = SH;                     // compact E re [32][72]
    float* const Eci = SH + 2304;              // compact E im
    float* const Per = SH + 4608;              // P even re [8][4][36]
    float* const Pei = SH + 5760;
    float* const Por = SH + 6912;              // P odd
    float* const Poi = SH + 8064;
    float* const Gr  = SH;                     // [b<=32][GS]   (E dead)
    float* const Gi  = SH + 2304;
    float* const hU  = SH;                     // [2000]        (G dead)
    float* const red = SH + 4608;              // [12][168]     (P dead)

    const int row   = blockIdx.x;
    const int batch = row / NFRAMES;
    const int frame = row - batch * NFRAMES;
    const int t0    = frame * PFRAME;
    const int t     = threadIdx.x;

    if (t < NCOEF) csh[t] = mc[row * NCOEF + t];

    // ---- async x-stage: issue global loads to regs now, LDS-write later --
    float xv[9];
    {
        const float* xb = x + batch * T_TOTAL;
        #pragma unroll
        for (int k = 0; k < 9; k++) {
            const int j  = t + 256 * k;
            const int xi = t0 - 2079 + j;
            xv[k] = (j < XWN && xi >= 0 && xi < T_TOTAL) ? xb[xi] : 0.0f;
        }
    }

    // ---- stagger: desynchronize co-resident blocks (bid, bid+256, +512) --
    {
        const int rph = blockIdx.x >> 8;       // 0,1,2
        if (rph == 1)      asm volatile("s_sleep 32");
        else if (rph == 2) asm volatile("s_sleep 64");
    }
    __syncthreads();   // csh visible

    // ---------------- phase E (Clenshaw, compact conjugate-mirror store) --
    {
        float creg[NCOEF];
        #pragma unroll
        for (int k = 0; k < NCOEF; k++) creg[k] = csh[k];

        // live-column bookkeeping: f%128 constant per thread (256|f-step)
        const int  m   = t & 127;
        const bool lD  = (m < 36) || (m >= 64 && m < 100);
        const int  cbD = (m < 64) ? m : m - 28;
        const int  mm  = (128 - m) & 127;
        const bool lM  = (mm < 36) || (mm >= 64 && mm < 100);
        const int  cbM = (mm < 64) ? mm : mm - 28;

        float bs, bc; fsincos(-(TWO_PI / 4096.0f) * (float)t, &bs, &bc);
        const float SC =  0.923879532511287f;   // cos(pi/8)
        const float SS = -0.382683432365090f;   // sin(-pi/8)
        #pragma unroll 4
        for (int ii = 0; ii < 8; ii++) {
            const int f = t + 256 * ii;                // 0..2047
            const float wc = bc, ws = bs;              // e^{-2pi i f/4096}
            { const float nr = bc * SC - bs * SS;      // advance base
              const float ni = bc * SS + bs * SC;
              bc = nr; bs = ni; }
            const float t2 = 2.0f * wc;
            float b1 = 0.0f, b2 = 0.0f;
            #pragma unroll
            for (int k = NCOEF - 1; k >= 1; k--) {
                const float bk = __fmaf_rn(t2, b1, creg[k] - b2);
                b2 = b1; b1 = bk;
            }
            const float Cr = __fmaf_rn(wc, b1, creg[0] - b2);
            const float Ci = ws * b1;
            const float mg = __expf(Cr);
            float si, co; fsincos(Ci, &si, &co);
            const float er = mg * co, ei = mg * si;
            const int aD = (t >> 7) + 2 * ii;          // f >> 7
            if (lD) { Ecr[72 * aD + cbD] = er; Eci[72 * aD + cbD] = ei; }
            if (f > 0 && lM) {
                const int aM = (m == 0) ? (32 - aD) : (31 - aD);
                Ecr[72 * aM + cbM] = er; Eci[72 * aM + cbM] = -ei;
            }
        }
        if (t == 0) {                                  // f = 2048: a2=16, cb=0
            float Cr = 0.0f, Ci = 0.0f;
            float cr = 1.0f, ci = 0.0f;
            #pragma unroll
            for (int k = 0; k < NCOEF; k++) {
                Cr += csh[k] * cr; Ci += csh[k] * ci;
                cr = -cr; ci = -ci;                    // e^{-i pi k} = (-1)^k
            }
            const float mg = __expf(Cr);
            float si, co; fsincos(Ci, &si, &co);
            Ecr[72 * 16] = mg * co; Eci[72 * 16] = mg * si;
        }
    }

    // ---- x regs -> LDS (global latency hidden under phase E) -------------
    #pragma unroll
    for (int k = 0; k < 9; k++) {
        const int j = t + 256 * k;
        if (j < XWN) xws[XPHYS(j)] = xv[k];
    }
    __syncthreads();

    // ---------- S1a: radix-4 over q (a2 = 8q + r), trivial twiddles -------
    // P[r][d4][b'] = sum_q E[a2=8q+r][b'] * i^(d4*q)
    if (t < 144) {
        const int bg = t % 9;                  // b-group 0..8
        const int rh = t / 9;                  // 0..15
        const int r  = rh & 7;
        const int h  = rh >> 3;                // 0 = even (b), 1 = odd (64+b)
        const int base = 72 * r + 36 * h + 4 * bg;
        float e0r[4], e1r[4], e2r[4], e3r[4];
        float e0i[4], e1i[4], e2i[4], e3i[4];
        {
            const float4 a = *(const float4*)&Ecr[base];
            const float4 b = *(const float4*)&Ecr[base + 576];
            const float4 c = *(const float4*)&Ecr[base + 1152];
            const float4 d = *(const float4*)&Ecr[base + 1728];
            e0r[0]=a.x; e0r[1]=a.y; e0r[2]=a.z; e0r[3]=a.w;
            e1r[0]=b.x; e1r[1]=b.y; e1r[2]=b.z; e1r[3]=b.w;
            e2r[0]=c.x; e2r[1]=c.y; e2r[2]=c.z; e2r[3]=c.w;
            e3r[0]=d.x; e3r[1]=d.y; e3r[2]=d.z; e3r[3]=d.w;
        }
        {
            const float4 a = *(const float4*)&Eci[base];
            const float4 b = *(const float4*)&Eci[base + 576];
            const float4 c = *(const float4*)&Eci[base + 1152];
            const float4 d = *(const float4*)&Eci[base + 1728];
            e0i[0]=a.x; e0i[1]=a.y; e0i[2]=a.z; e0i[3]=a.w;
            e1i[0]=b.x; e1i[1]=b.y; e1i[2]=b.z; e1i[3]=b.w;
            e2i[0]=c.x; e2i[1]=c.y; e2i[2]=c.z; e2i[3]=c.w;
            e3i[0]=d.x; e3i[1]=d.y; e3i[2]=d.z; e3i[3]=d.w;
        }
        float p0r[4], p0i[4], p1r[4], p1i[4];
        float p2r[4], p2i[4], p3r[4], p3i[4];
        #pragma unroll
        for (int i = 0; i < 4; i++) {
            const float Ar = e0r[i] + e2r[i], Ai = e0i[i] + e2i[i];
            const float Br = e0r[i] - e2r[i], Bi = e0i[i] - e2i[i];
            const float Cr = e1r[i] + e3r[i], Ci = e1i[i] + e3i[i];
            const float Dr = e1r[i] - e3r[i], Di = e1i[i] - e3i[i];
            p0r[i] = Ar + Cr;  p0i[i] = Ai + Ci;      // d4=0
            p2r[i] = Ar - Cr;  p2i[i] = Ai - Ci;      // d4=2
            p1r[i] = Br - Di;  p1i[i] = Bi + Dr;      // d4=1: B + iD
            p3r[i] = Br + Di;  p3i[i] = Bi - Dr;      // d4=3: B - iD
        }
        float* const Qr = (h ? Por : Per);
        float* const Qi = (h ? Poi : Pei);
        const int pb = 144 * r + 4 * bg;
        *(float4*)&Qr[pb]       = make_float4(p0r[0], p0r[1], p0r[2], p0r[3]);
        *(float4*)&Qi[pb]       = make_float4(p0i[0], p0i[1], p0i[2], p0i[3]);
        *(float4*)&Qr[pb + 36]  = make_float4(p1r[0], p1r[1], p1r[2], p1r[3]);
        *(float4*)&Qi[pb + 36]  = make_float4(p1i[0], p1i[1], p1i[2], p1i[3]);
        *(float4*)&Qr[pb + 72]  = make_float4(p2r[0], p2r[1], p2r[2], p2r[3]);
        *(float4*)&Qi[pb + 72]  = make_float4(p2i[0], p2i[1], p2i[2], p2i[3]);
        *(float4*)&Qr[pb + 108] = make_float4(p3r[0], p3r[1], p3r[2], p3r[3]);
        *(float4*)&Qi[pb + 108] = make_float4(p3i[0], p3i[1], p3i[2], p3i[3]);
    }
    __syncthreads();   // P ready; ALL E reads done (G may overwrite E)

    // ---------- S1b: radix-8 over r (proven loop, a2->r, E->P) ------------
    {
        const bool act = t < 144;
        const int bg = t % 9;                  // b-group 0..8  (b0 = 0..32)
        const int dp = t / 9;                  // d-pair 0..15
        const int b0 = bg * 4;
        const int d0 = dp * 2;
        float Ter[2][4], Tei[2][4], Tor[2][4], Toi[2][4];
        #pragma unroll
        for (int j = 0; j < 2; j++)
            #pragma unroll
            for (int i = 0; i < 4; i++) {
                Ter[j][i] = 0.0f; Tei[j][i] = 0.0f;
                Tor[j][i] = 0.0f; Toi[j][i] = 0.0f;
            }
        if (act) {
            #pragma unroll
            for (int j = 0; j < 2; j++) {
                const int d  = d0 + j;
                const int pb = 36 * (d & 3) + b0;
                float s, c; fsincos((TWO_PI / 32.0f) * (float)d, &s, &c);
                const float wr = c, wi = s;
                float rr = 1.0f, ri = 0.0f;
                #pragma unroll
                for (int r8 = 0; r8 < 8; r8++) {
                    const int pa = 144 * r8 + pb;
                    const float4 vpr = *(const float4*)&Per[pa];
                    const float4 vpi = *(const float4*)&Pei[pa];
                    const float4 vqr = *(const float4*)&Por[pa];
                    const float4 vqi = *(const float4*)&Poi[pa];
                    const float per_[4] = {vpr.x, vpr.y, vpr.z, vpr.w};
                    const float pei_[4] = {vpi.x, vpi.y, vpi.z, vpi.w};
                    const float por_[4] = {vqr.x, vqr.y, vqr.z, vqr.w};
                    const float poi_[4] = {vqi.x, vqi.y, vqi.z, vqi.w};
                    #pragma unroll
                    for (int i = 0; i < 4; i++) {
                        Ter[j][i] += per_[i] * rr - pei_[i] * ri;
                        Tei[j][i] += per_[i] * ri + pei_[i] * rr;
                        Tor[j][i] += por_[i] * rr - poi_[i] * ri;
                        Toi[j][i] += por_[i] * ri + poi_[i] * rr;
                    }
                    const float nr = rr * wr - ri * wi;
                    const float ni = rr * wi + ri * wr;
                    rr = nr; ri = ni;
                }
            }
            // radix-2 butterfly + bd/4096 twiddle + store (b <= 32 only)
            float os[2], oc[2];
            #pragma unroll
            for (int j = 0; j < 2; j++)
                fsincos((TWO_PI / 64.0f) * (float)(d0 + j), &os[j], &oc[j]);
            #pragma unroll
            for (int i = 0; i < 4; i++) {
                const int b = b0 + i;
                if (b > 32) continue;
                float gpr[2], gpi[2], gmr[2], gmi[2];
                #pragma unroll
                for (int j = 0; j < 2; j++) {
                    const int d = d0 + j;
                    const float ur = oc[j] * Tor[j][i] - os[j] * Toi[j][i];
                    const float ui = oc[j] * Toi[j][i] + os[j] * Tor[j][i];
                    const float pr = Ter[j][i] + ur, pi = Tei[j][i] + ui;
                    const float mr = Ter[j][i] - ur, mi = Tei[j][i] - ui;
                    float s, c;
                    fsincos((TWO_PI / 4096.0f) * (float)(b * d), &s, &c);
                    gpr[j] = pr * c - pi * s; gpi[j] = pr * s + pi * c;
                    fsincos((TWO_PI / 4096.0f) * (float)(b * (d + 32)), &s, &c);
                    gmr[j] = mr * c - mi * s; gmi[j] = mr * s + mi * c;
                }
                *(float2*)&Gr[b * GS + d0]      = make_float2(gpr[0], gpr[1]);
                *(float2*)&Gi[b * GS + d0]      = make_float2(gpi[0], gpi[1]);
                *(float2*)&Gr[b * GS + d0 + 32] = make_float2(gmr[0], gmr[1]);
                *(float2*)&Gi[b * GS + d0 + 32] = make_float2(gmi[0], gmi[1]);
            }
        }
    }
    __syncthreads();

    // ---------------- stage 2 (R17 rolled loop, 4 groups = b 0..31) -------
    float hv[4][2];
    int   dl_, cg_;
    {
        const int dl = (t & 31) * 2;
        const int cg = t >> 5;                     // 0..7
        dl_ = dl; cg_ = cg;
        float swi_, swr_; fsincos((TWO_PI / 64.0f) * (float)cg, &swi_, &swr_);
        const float swr = swr_, swi = swi_;        // step e^{2pi i cg/64}
        float rr = 1.0f, ri = 0.0f;
        float acc00 = 0, acc01 = 0, acc10 = 0, acc11 = 0;
        float acc20 = 0, acc21 = 0, acc30 = 0, acc31 = 0;
        int bb = 0;

#define S2C 0.70710678118654752f
#define STEP2(f8r, f8i, f16r, f16i, f24r, f24i)                                \
        {                                                                      \
            const float2 g_r = *(const float2*)&Gr[bb * GS + dl];              \
            const float2 g_i = *(const float2*)&Gi[bb * GS + dl];              \
            acc00 += g_r.x * rr - g_i.x * ri;                                  \
            acc01 += g_r.y * rr - g_i.y * ri;                                  \
            { const float tr = rr*(f8r) - ri*(f8i), ti = rr*(f8i) + ri*(f8r);  \
              acc10 += g_r.x * tr - g_i.x * ti;                                \
              acc11 += g_r.y * tr - g_i.y * ti; }                              \
            { const float tr = rr*(f16r) - ri*(f16i), ti = rr*(f16i) + ri*(f16r); \
              acc20 += g_r.x * tr - g_i.x * ti;                                \
              acc21 += g_r.y * tr - g_i.y * ti; }                              \
            { const float tr = rr*(f24r) - ri*(f24i), ti = rr*(f24i) + ri*(f24r); \
              acc30 += g_r.x * tr - g_i.x * ti;                                \
              acc31 += g_r.y * tr - g_i.y * ti; }                              \
            { const float nr = rr * swr - ri * swi;                            \
              const float ni = rr * swi + ri * swr;                            \
              rr = nr; ri = ni; }                                              \
            bb++;                                                              \
        }

        #pragma unroll 1
        for (int grp = 0; grp < 4; grp++) {        // b = 0..31 (rolled!)
            STEP2( 1.0f, 0.0f,   1.0f, 0.0f,   1.0f, 0.0f)
            STEP2( S2C,  S2C,    0.0f, 1.0f,  -S2C,  S2C)
            STEP2( 0.0f, 1.0f,  -1.0f, 0.0f,   0.0f,-1.0f)
            STEP2(-S2C,  S2C,    0.0f,-1.0f,   S2C,  S2C)
            STEP2(-1.0f, 0.0f,   1.0f, 0.0f,  -1.0f, 0.0f)
            STEP2(-S2C, -S2C,    0.0f, 1.0f,   S2C, -S2C)
            STEP2( 0.0f,-1.0f,  -1.0f, 0.0f,   0.0f, 1.0f)
            STEP2( S2C, -S2C,    0.0f,-1.0f,  -S2C, -S2C)
        }
#undef STEP2

        // Hermitian fixup: true sum = 2*acc - g0 + (-1)^cg * g32, /4096
        const float g0a  = Gr[dl],           g0b  = Gr[dl + 1];
        const float g32a = Gr[32 * GS + dl], g32b = Gr[32 * GS + dl + 1];
        const float sgn  = (cg & 1) ? -1.0f : 1.0f;
        const float sc = 1.0f / 4096.0f;
        hv[0][0] = (2.0f * acc00 - g0a + sgn * g32a) * sc;
        hv[0][1] = (2.0f * acc01 - g0b + sgn * g32b) * sc;
        hv[1][0] = (2.0f * acc10 - g0a + sgn * g32a) * sc;
        hv[1][1] = (2.0f * acc11 - g0b + sgn * g32b) * sc;
        hv[2][0] = (2.0f * acc20 - g0a + sgn * g32a) * sc;
        hv[2][1] = (2.0f * acc21 - g0b + sgn * g32b) * sc;
        hv[3][0] = (2.0f * acc30 - g0a + sgn * g32a) * sc;
        hv[3][1] = (2.0f * acc31 - g0b + sgn * g32b) * sc;
    }
    __syncthreads();   // all G reads done; SH is free

    // ---------------- h -> LDS ----------------
    #pragma unroll
    for (int v = 0; v < 4; v++) {
        const int c = cg_ + 8 * v;
        const int n = 64 * c + dl_;
        if (n < IR_LEN)     hU[n]     = hv[v][0];
        if (n + 1 < IR_LEN) hU[n + 1] = hv[v][1];
    }
    __syncthreads();

    // ---------------- FIR: z[o], o in [0,160) ----------------
    if (t < 240) {
        const int o0 = (t % 20) * 8;
        const int kc = t / 20;                 // 0..11
        const int kb = kc * 168;
        const int ns = (kc == 11) ? 38 : 42;   // 11*168=1848, +152 = 2000
        float s0[8] = {0,0,0,0,0,0,0,0};
        int Bo = o0 + 1996 - kb;               // mult of 4, >= 0
        float4 w1 = *(const float4*)&xws[XPHYS(Bo + 4)];
        float4 w2 = *(const float4*)&xws[XPHYS(Bo + 8)];
        for (int s = 0; s < ns; s++) {
            const float4 w0 = *(const float4*)&xws[XPHYS(Bo)];
            const float4 ha = *(const float4*)&hU[kb + 4 * s];
            const float wv[12] = {w0.x, w0.y, w0.z, w0.w,
                                  w1.x, w1.y, w1.z, w1.w,
                                  w2.x, w2.y, w2.z, w2.w};
            const float hav[4] = {ha.x, ha.y, ha.z, ha.w};
            #pragma unroll
            for (int jo = 0; jo < 8; jo++) {
                #pragma unroll
                for (int jk = 0; jk < 4; jk++) {
                    s0[jo] += hav[jk] * wv[3 + jo - jk];
                }
            }
            w2 = w1; w1 = w0; Bo -= 4;
        }
        const int rb = kc * 168 + o0;
        *(float4*)&red[rb]     = make_float4(s0[0], s0[1], s0[2], s0[3]);
        *(float4*)&red[rb + 4] = make_float4(s0[4], s0[5], s0[6], s0[7]);
    }
    __syncthreads();

    // ---------------- epilogue: tent-weighted atomic scatter ----------------
    if (t < 160) {
        float z = 0.0f;
        #pragma unroll
        for (int kc = 0; kc < 12; kc++) z += red[kc * 168 + t];
        const int o = t;
        const int tout = t0 - PFRAME + o;
        float wgt = (o < PFRAME) ? (float)o * (1.0f / PFRAME)
                                 : (float)(160 - o) * (1.0f / PFRAME);
        if (frame == NFRAMES - 1 && o >= PFRAME) wgt = 1.0f;  // clamped h_next
        if (tout >= 0) {                       // frame 0 has no previous frame
            atomicAdd(&y[batch * T_TOTAL + tout], wgt * z);
        }
    }
}

extern "C" void kernel_launch(void* const* d_in, const int* in_sizes, int n_in,
                              void* d_out, int out_size, void* d_ws, size_t ws_size,
                              hipStream_t stream) {
    const float* x  = (const float*)d_in[0];   // (2, 24000)
    const float* mc = (const float*)d_in[1];   // (2, 300, 25)
    float* y = (float*)d_out;                  // (2, 24000)

    hipMemsetAsync(y, 0, (size_t)out_size * sizeof(float), stream);
    minphase_fir_fused<<<NROWS, 256, 0, stream>>>(mc, x, y);
}

// Round 9
// 87.154 us; speedup vs baseline: 1.0898x; 1.0898x over previous
//
#include <hip/hip_runtime.h>
#include <math.h>

#define IR_LEN  2000
#define PFRAME  80
#define NFRAMES 300
#define NBATCH  2
#define NROWS   (NBATCH*NFRAMES)     // 600
#define T_TOTAL (NFRAMES*PFRAME)     // 24000
#define NCOEF   25
#define TWO_PI  6.283185307179586f
#define GS      68                   // G row stride in floats
#define XWN     2160                 // logical x-window floats per block
#define XWPAD   2432                 // physical (4-float pad per 32)

#define XPHYS(B) ((B) + (((B) >> 5) << 2))

__device__ __forceinline__ void fsincos(float a, float* s, float* c) {
    *s = __sinf(a); *c = __cosf(a);
}

// ---------------------------------------------------------------------------
// R25 = R23 revert (proven best: ~38.5 us kernel / 86.3 bench; R24's
// radix-split REVERTED: VGPR 72->168 halved occupancy, +9 us bench) + ONE
// knob change: DEEPER entry stagger. R23's sleeps (0.85/1.7 us) were shorter
// than one phase (E ~ 3-4 us), so co-resident blocks only partially
// de-phased. rph=1 -> s_sleep 64 (~1.7 us), rph=2 -> s_sleep 127 (~3.4 us,
// 7-bit max) offsets the three co-resident rounds by ~a full phase each.
// Everything else is R23 verbatim (Clenshaw E, async x-stage, R16 S1/S2/FIR).
// ---------------------------------------------------------------------------
__global__ __launch_bounds__(256) void minphase_fir_fused(
        const float* __restrict__ mc, const float* __restrict__ x,
        float* __restrict__ y) {
    __shared__ __align__(16) float U[8704];    // 34.8 KB union
    __shared__ __align__(16) float xws[XWPAD]; // 9.7 KB padded x window
    __shared__ float csh[NCOEF];
    float* const EHr = U;                      // [4096]      (phase E)
    float* const EHi = U + 4096;               // [4096]
    float* const Gr  = U;                      // [rows b<=32] (stages 1/2)
    float* const Gi  = U + 4352;               // [rows b<=32]
    float* const hU  = U;                      // [2000]      (FIR phase)
    float* const red = U + 4224;               // [12 rows, stride 168]

    const int row   = blockIdx.x;
    const int batch = row / NFRAMES;
    const int frame = row - batch * NFRAMES;
    const int t0    = frame * PFRAME;
    const int t     = threadIdx.x;

    if (t < NCOEF) csh[t] = mc[row * NCOEF + t];

    // ---- async x-stage: issue global loads to regs now, LDS-write later --
    float xv[9];
    {
        const float* xb = x + batch * T_TOTAL;
        #pragma unroll
        for (int k = 0; k < 9; k++) {
            const int j  = t + 256 * k;
            const int xi = t0 - 2079 + j;
            xv[k] = (j < XWN && xi >= 0 && xi < T_TOTAL) ? xb[xi] : 0.0f;
        }
    }

    // ---- stagger: desynchronize co-resident blocks (bid, bid+256, +512) --
    {
        const int rph = blockIdx.x >> 8;       // 0,1,2
        if (rph == 1)      asm volatile("s_sleep 64");    // ~4096 cyc ~1.7us
        else if (rph == 2) asm volatile("s_sleep 127");   // ~8128 cyc ~3.4us
    }
    __syncthreads();   // csh visible

    // ---------------- phase E (Clenshaw, conjugate mirror, chained base) --
    {
        float creg[NCOEF];
        #pragma unroll
        for (int k = 0; k < NCOEF; k++) creg[k] = csh[k];

        float bs, bc; fsincos(-(TWO_PI / 4096.0f) * (float)t, &bs, &bc);
        const float SC =  0.923879532511287f;   // cos(pi/8)
        const float SS = -0.382683432365090f;   // sin(-pi/8)
        #pragma unroll 4
        for (int ii = 0; ii < 8; ii++) {
            const int f = t + 256 * ii;                // 0..2047
            const float wc = bc, ws = bs;              // e^{-2pi i f/4096}
            { const float nr = bc * SC - bs * SS;      // advance base
              const float ni = bc * SS + bs * SC;
              bc = nr; bs = ni; }
            const float t2 = 2.0f * wc;
            float b1 = 0.0f, b2 = 0.0f;
            #pragma unroll
            for (int k = NCOEF - 1; k >= 1; k--) {
                const float bk = __fmaf_rn(t2, b1, creg[k] - b2);
                b2 = b1; b1 = bk;
            }
            const float Cr = __fmaf_rn(wc, b1, creg[0] - b2);
            const float Ci = ws * b1;
            const float m = __expf(Cr);
            float si, co; fsincos(Ci, &si, &co);
            const float er = m * co, ei = m * si;
            EHr[f] = er; EHi[f] = ei;
            if (f > 0) { EHr[4096 - f] = er; EHi[4096 - f] = -ei; }
        }
        if (t == 0) {                                  // f = 2048
            float Cr = 0.0f, Ci = 0.0f;
            float cr = 1.0f, ci = 0.0f;
            #pragma unroll
            for (int k = 0; k < NCOEF; k++) {
                Cr += csh[k] * cr; Ci += csh[k] * ci;
                cr = -cr; ci = -ci;                    // e^{-i pi k} = (-1)^k
            }
            const float m = __expf(Cr);
            float si, co; fsincos(Ci, &si, &co);
            EHr[2048] = m * co; EHi[2048] = m * si;
        }
    }

    // ---- x regs -> LDS (global latency was hidden under phase E) --------
    #pragma unroll
    for (int k = 0; k < 9; k++) {
        const int j = t + 256 * k;
        if (j < XWN) xws[XPHYS(j)] = xv[k];
    }
    __syncthreads();

    // ------- stage 1 (R16 shape, wave-contiguous Hermitian tiles) ---------
    {
        const bool act = t < 144;              // waves 0-1 dense, w2 1/4, w3 off
        const int bg = t % 9;                  // b-group 0..8  (b0 = 0..32)
        const int dp = t / 9;                  // d-pair 0..15  (for t < 144)
        const int b0 = bg * 4;
        const int d0 = dp * 2;
        float Ter[2][4], Tei[2][4], Tor[2][4], Toi[2][4];
        #pragma unroll
        for (int j = 0; j < 2; j++)
            #pragma unroll
            for (int i = 0; i < 4; i++) {
                Ter[j][i] = 0.0f; Tei[j][i] = 0.0f;
                Tor[j][i] = 0.0f; Toi[j][i] = 0.0f;
            }
        float rr[2], ri[2], wr[2], wi[2];
        if (act) {
            #pragma unroll
            for (int j = 0; j < 2; j++) {
                float s, c; fsincos((TWO_PI / 32.0f) * (float)(d0 + j), &s, &c);
                wr[j] = c; wi[j] = s; rr[j] = 1.0f; ri[j] = 0.0f;
            }
            // explicit prefetch double-buffer over a2 (R16 verbatim)
            float4 vre = *(const float4*)&EHr[b0];
            float4 vie = *(const float4*)&EHi[b0];
            float4 vro = *(const float4*)&EHr[64 + b0];
            float4 vio = *(const float4*)&EHi[64 + b0];
            #pragma unroll 4
            for (int a2 = 0; a2 < 32; a2++) {
                const float4 cre = vre, cie = vie, cro = vro, cio = vio;
                if (a2 < 31) {
                    const int nb = 128 * (a2 + 1) + b0;
                    vre = *(const float4*)&EHr[nb];
                    vie = *(const float4*)&EHi[nb];
                    vro = *(const float4*)&EHr[nb + 64];
                    vio = *(const float4*)&EHi[nb + 64];
                }
                const float ere[4] = {cre.x, cre.y, cre.z, cre.w};
                const float eie[4] = {cie.x, cie.y, cie.z, cie.w};
                const float ero[4] = {cro.x, cro.y, cro.z, cro.w};
                const float eio[4] = {cio.x, cio.y, cio.z, cio.w};
                #pragma unroll
                for (int j = 0; j < 2; j++) {
                    #pragma unroll
                    for (int i = 0; i < 4; i++) {
                        Ter[j][i] += ere[i] * rr[j] - eie[i] * ri[j];
                        Tei[j][i] += ere[i] * ri[j] + eie[i] * rr[j];
                        Tor[j][i] += ero[i] * rr[j] - eio[i] * ri[j];
                        Toi[j][i] += ero[i] * ri[j] + eio[i] * rr[j];
                    }
                    const float nr = rr[j] * wr[j] - ri[j] * wi[j];
                    const float ni = rr[j] * wi[j] + ri[j] * wr[j];
                    rr[j] = nr; ri[j] = ni;
                }
            }
        }
        __syncthreads();   // uniform barrier: ALL E reads done before G' store

        if (act) {
            // radix-2 butterfly + bd/4096 twiddle + store (b <= 32 only)
            float os[2], oc[2];
            #pragma unroll
            for (int j = 0; j < 2; j++)
                fsincos((TWO_PI / 64.0f) * (float)(d0 + j), &os[j], &oc[j]);
            #pragma unroll
            for (int i = 0; i < 4; i++) {
                const int b = b0 + i;
                if (b > 32) continue;
                float gpr[2], gpi[2], gmr[2], gmi[2];
                #pragma unroll
                for (int j = 0; j < 2; j++) {
                    const int d = d0 + j;
                    const float ur = oc[j] * Tor[j][i] - os[j] * Toi[j][i];
                    const float ui = oc[j] * Toi[j][i] + os[j] * Tor[j][i];
                    const float pr = Ter[j][i] + ur, pi = Tei[j][i] + ui;
                    const float mr = Ter[j][i] - ur, mi = Tei[j][i] - ui;
                    float s, c;
                    fsincos((TWO_PI / 4096.0f) * (float)(b * d), &s, &c);
                    gpr[j] = pr * c - pi * s; gpi[j] = pr * s + pi * c;
                    fsincos((TWO_PI / 4096.0f) * (float)(b * (d + 32)), &s, &c);
                    gmr[j] = mr * c - mi * s; gmi[j] = mr * s + mi * c;
                }
                *(float2*)&Gr[b * GS + d0]      = make_float2(gpr[0], gpr[1]);
                *(float2*)&Gi[b * GS + d0]      = make_float2(gpi[0], gpi[1]);
                *(float2*)&Gr[b * GS + d0 + 32] = make_float2(gmr[0], gmr[1]);
                *(float2*)&Gi[b * GS + d0 + 32] = make_float2(gmi[0], gmi[1]);
            }
        }
    }
    __syncthreads();

    // ---------------- stage 2 (R17 rolled loop, 4 groups = b 0..31) -------
    float hv[4][2];
    int   dl_, cg_;
    {
        const int dl = (t & 31) * 2;
        const int cg = t >> 5;                     // 0..7
        dl_ = dl; cg_ = cg;
        float swi_, swr_; fsincos((TWO_PI / 64.0f) * (float)cg, &swi_, &swr_);
        const float swr = swr_, swi = swi_;        // step e^{2pi i cg/64}
        float rr = 1.0f, ri = 0.0f;
        float acc00 = 0, acc01 = 0, acc10 = 0, acc11 = 0;
        float acc20 = 0, acc21 = 0, acc30 = 0, acc31 = 0;
        int bb = 0;

#define S2C 0.70710678118654752f
#define STEP2(f8r, f8i, f16r, f16i, f24r, f24i)                                \
        {                                                                      \
            const float2 g_r = *(const float2*)&Gr[bb * GS + dl];              \
            const float2 g_i = *(const float2*)&Gi[bb * GS + dl];              \
            acc00 += g_r.x * rr - g_i.x * ri;                                  \
            acc01 += g_r.y * rr - g_i.y * ri;                                  \
            { const float tr = rr*(f8r) - ri*(f8i), ti = rr*(f8i) + ri*(f8r);  \
              acc10 += g_r.x * tr - g_i.x * ti;                                \
              acc11 += g_r.y * tr - g_i.y * ti; }                              \
            { const float tr = rr*(f16r) - ri*(f16i), ti = rr*(f16i) + ri*(f16r); \
              acc20 += g_r.x * tr - g_i.x * ti;                                \
              acc21 += g_r.y * tr - g_i.y * ti; }                              \
            { const float tr = rr*(f24r) - ri*(f24i), ti = rr*(f24i) + ri*(f24r); \
              acc30 += g_r.x * tr - g_i.x * ti;                                \
              acc31 += g_r.y * tr - g_i.y * ti; }                              \
            { const float nr = rr * swr - ri * swi;                            \
              const float ni = rr * swi + ri * swr;                            \
              rr = nr; ri = ni; }                                              \
            bb++;                                                              \
        }

        #pragma unroll 1
        for (int grp = 0; grp < 4; grp++) {        // b = 0..31 (rolled!)
            STEP2( 1.0f, 0.0f,   1.0f, 0.0f,   1.0f, 0.0f)
            STEP2( S2C,  S2C,    0.0f, 1.0f,  -S2C,  S2C)
            STEP2( 0.0f, 1.0f,  -1.0f, 0.0f,   0.0f,-1.0f)
            STEP2(-S2C,  S2C,    0.0f,-1.0f,   S2C,  S2C)
            STEP2(-1.0f, 0.0f,   1.0f, 0.0f,  -1.0f, 0.0f)
            STEP2(-S2C, -S2C,    0.0f, 1.0f,   S2C, -S2C)
            STEP2( 0.0f,-1.0f,  -1.0f, 0.0f,   0.0f, 1.0f)
            STEP2( S2C, -S2C,    0.0f,-1.0f,  -S2C, -S2C)
        }
#undef STEP2

        // Hermitian fixup: true sum = 2*acc - g0 + (-1)^cg * g32, /4096
        const float g0a  = Gr[dl],           g0b  = Gr[dl + 1];
        const float g32a = Gr[32 * GS + dl], g32b = Gr[32 * GS + dl + 1];
        const float sgn  = (cg & 1) ? -1.0f : 1.0f;   // (-1)^{cg+8v} = (-1)^cg
        const float sc = 1.0f / 4096.0f;
        hv[0][0] = (2.0f * acc00 - g0a + sgn * g32a) * sc;
        hv[0][1] = (2.0f * acc01 - g0b + sgn * g32b) * sc;
        hv[1][0] = (2.0f * acc10 - g0a + sgn * g32a) * sc;
        hv[1][1] = (2.0f * acc11 - g0b + sgn * g32b) * sc;
        hv[2][0] = (2.0f * acc20 - g0a + sgn * g32a) * sc;
        hv[2][1] = (2.0f * acc21 - g0b + sgn * g32b) * sc;
        hv[3][0] = (2.0f * acc30 - g0a + sgn * g32a) * sc;
        hv[3][1] = (2.0f * acc31 - g0b + sgn * g32b) * sc;
    }
    __syncthreads();   // all G reads done; U is free

    // ---------------- h -> LDS ----------------
    #pragma unroll
    for (int v = 0; v < 4; v++) {
        const int c = cg_ + 8 * v;
        const int n = 64 * c + dl_;
        if (n < IR_LEN)     hU[n]     = hv[v][0];
        if (n + 1 < IR_LEN) hU[n + 1] = hv[v][1];
    }
    __syncthreads();

    // ---------------- FIR: z[o], o in [0,160) ----------------
    if (t < 240) {
        const int o0 = (t % 20) * 8;
        const int kc = t / 20;                 // 0..11
        const int kb = kc * 168;
        const int ns = (kc == 11) ? 38 : 42;   // 11*168=1848, +152 = 2000
        float s0[8] = {0,0,0,0,0,0,0,0};
        int Bo = o0 + 1996 - kb;               // mult of 4, >= 0
        float4 w1 = *(const float4*)&xws[XPHYS(Bo + 4)];
        float4 w2 = *(const float4*)&xws[XPHYS(Bo + 8)];
        for (int s = 0; s < ns; s++) {
            const float4 w0 = *(const float4*)&xws[XPHYS(Bo)];
            const float4 ha = *(const float4*)&hU[kb + 4 * s];
            const float wv[12] = {w0.x, w0.y, w0.z, w0.w,
                                  w1.x, w1.y, w1.z, w1.w,
                                  w2.x, w2.y, w2.z, w2.w};
            const float hav[4] = {ha.x, ha.y, ha.z, ha.w};
            #pragma unroll
            for (int jo = 0; jo < 8; jo++) {
                #pragma unroll
                for (int jk = 0; jk < 4; jk++) {
                    s0[jo] += hav[jk] * wv[3 + jo - jk];
                }
            }
            w2 = w1; w1 = w0; Bo -= 4;
        }
        const int rb = kc * 168 + o0;
        *(float4*)&red[rb]     = make_float4(s0[0], s0[1], s0[2], s0[3]);
        *(float4*)&red[rb + 4] = make_float4(s0[4], s0[5], s0[6], s0[7]);
    }
    __syncthreads();

    // ---------------- epilogue: tent-weighted atomic scatter ----------------
    if (t < 160) {
        float z = 0.0f;
        #pragma unroll
        for (int kc = 0; kc < 12; kc++) z += red[kc * 168 + t];
        const int o = t;
        const int tout = t0 - PFRAME + o;
        float wgt = (o < PFRAME) ? (float)o * (1.0f / PFRAME)
                                 : (float)(160 - o) * (1.0f / PFRAME);
        if (frame == NFRAMES - 1 && o >= PFRAME) wgt = 1.0f;  // clamped h_next
        if (tout >= 0) {                       // frame 0 has no previous frame
            atomicAdd(&y[batch * T_TOTAL + tout], wgt * z);
        }
    }
}

extern "C" void kernel_launch(void* const* d_in, const int* in_sizes, int n_in,
                              void* d_out, int out_size, void* d_ws, size_t ws_size,
                              hipStream_t stream) {
    const float* x  = (const float*)d_in[0];   // (2, 24000)
    const float* mc = (const float*)d_in[1];   // (2, 300, 25)
    float* y = (float*)d_out;                  // (2, 24000)

    hipMemsetAsync(y, 0, (size_t)out_size * sizeof(float), stream);
    minphase_fir_fused<<<NROWS, 256, 0, stream>>>(mc, x, y);
}

// Round 10
// 86.898 us; speedup vs baseline: 1.0930x; 1.0029x over previous
//
#include <hip/hip_runtime.h>
#include <math.h>

#define IR_LEN  2000
#define PFRAME  80
#define NFRAMES 300
#define NBATCH  2
#define NROWS   (NBATCH*NFRAMES)     // 600
#define T_TOTAL (NFRAMES*PFRAME)     // 24000
#define NCOEF   25
#define TWO_PI  6.283185307179586f
#define GS      68                   // G row stride in floats
#define XWN     2160                 // logical x-window floats per block
#define XWPAD   2432                 // physical (4-float pad per 32)

#define XPHYS(B) ((B) + (((B) >> 5) << 2))

__device__ __forceinline__ void fsincos(float a, float* s, float* c) {
    *s = __sinf(a); *c = __cosf(a);
}

// ---------------------------------------------------------------------------
// R26 = R23 verbatim revert (the proven best: ~38.5-39.5 us kernel / 86.3
// bench). Dose-response on entry stagger resolved by R25: 32/64 sleeps are
// optimal (none=41.0, 32/64=38.5-39.5, 64/127=40.8 -> tail cost dominates).
// Session scoreboard: R17 Clenshaw flat, R19 512-thr -37%, R20 prefetch null,
// R22 split -6%, R24 radix-S1 -9% (VGPR 168), R25 deep stagger -1%;
// R23 stagger+async-x is the only measured win. This locks it in.
//   (1) entry STAGGER 32/64: co-resident blocks (bid, bid+256, bid+512) run
//       different phases concurrently -> complementary pipe use.
//   (2) async x-stage (T14): x-window global loads issued to regs at top,
//       ds_write after phase E (HBM latency hidden under E compute).
// Everything else (E Clenshaw, R16 S1/S2/FIR/epilogue) proven since R16/R17.
// ---------------------------------------------------------------------------
__global__ __launch_bounds__(256) void minphase_fir_fused(
        const float* __restrict__ mc, const float* __restrict__ x,
        float* __restrict__ y) {
    __shared__ __align__(16) float U[8704];    // 34.8 KB union
    __shared__ __align__(16) float xws[XWPAD]; // 9.7 KB padded x window
    __shared__ float csh[NCOEF];
    float* const EHr = U;                      // [4096]      (phase E)
    float* const EHi = U + 4096;               // [4096]
    float* const Gr  = U;                      // [rows b<=32] (stages 1/2)
    float* const Gi  = U + 4352;               // [rows b<=32]
    float* const hU  = U;                      // [2000]      (FIR phase)
    float* const red = U + 4224;               // [12 rows, stride 168]

    const int row   = blockIdx.x;
    const int batch = row / NFRAMES;
    const int frame = row - batch * NFRAMES;
    const int t0    = frame * PFRAME;
    const int t     = threadIdx.x;

    if (t < NCOEF) csh[t] = mc[row * NCOEF + t];

    // ---- async x-stage: issue global loads to regs now, LDS-write later --
    float xv[9];
    {
        const float* xb = x + batch * T_TOTAL;
        #pragma unroll
        for (int k = 0; k < 9; k++) {
            const int j  = t + 256 * k;
            const int xi = t0 - 2079 + j;
            xv[k] = (j < XWN && xi >= 0 && xi < T_TOTAL) ? xb[xi] : 0.0f;
        }
    }

    // ---- stagger: desynchronize co-resident blocks (bid, bid+256, +512) --
    {
        const int rph = blockIdx.x >> 8;       // 0,1,2
        if (rph == 1)      asm volatile("s_sleep 32");   // ~2048 cyc
        else if (rph == 2) asm volatile("s_sleep 64");   // ~4096 cyc
    }
    __syncthreads();   // csh visible

    // ---------------- phase E (Clenshaw, conjugate mirror, chained base) --
    {
        float creg[NCOEF];
        #pragma unroll
        for (int k = 0; k < NCOEF; k++) creg[k] = csh[k];

        float bs, bc; fsincos(-(TWO_PI / 4096.0f) * (float)t, &bs, &bc);
        const float SC =  0.923879532511287f;   // cos(pi/8)
        const float SS = -0.382683432365090f;   // sin(-pi/8)
        #pragma unroll 4
        for (int ii = 0; ii < 8; ii++) {
            const int f = t + 256 * ii;                // 0..2047
            const float wc = bc, ws = bs;              // e^{-2pi i f/4096}
            { const float nr = bc * SC - bs * SS;      // advance base
              const float ni = bc * SS + bs * SC;
              bc = nr; bs = ni; }
            const float t2 = 2.0f * wc;
            float b1 = 0.0f, b2 = 0.0f;
            #pragma unroll
            for (int k = NCOEF - 1; k >= 1; k--) {
                const float bk = __fmaf_rn(t2, b1, creg[k] - b2);
                b2 = b1; b1 = bk;
            }
            const float Cr = __fmaf_rn(wc, b1, creg[0] - b2);
            const float Ci = ws * b1;
            const float m = __expf(Cr);
            float si, co; fsincos(Ci, &si, &co);
            const float er = m * co, ei = m * si;
            EHr[f] = er; EHi[f] = ei;
            if (f > 0) { EHr[4096 - f] = er; EHi[4096 - f] = -ei; }
        }
        if (t == 0) {                                  // f = 2048
            float Cr = 0.0f, Ci = 0.0f;
            float cr = 1.0f, ci = 0.0f;
            #pragma unroll
            for (int k = 0; k < NCOEF; k++) {
                Cr += csh[k] * cr; Ci += csh[k] * ci;
                cr = -cr; ci = -ci;                    // e^{-i pi k} = (-1)^k
            }
            const float m = __expf(Cr);
            float si, co; fsincos(Ci, &si, &co);
            EHr[2048] = m * co; EHi[2048] = m * si;
        }
    }

    // ---- x regs -> LDS (global latency was hidden under phase E) --------
    #pragma unroll
    for (int k = 0; k < 9; k++) {
        const int j = t + 256 * k;
        if (j < XWN) xws[XPHYS(j)] = xv[k];
    }
    __syncthreads();

    // ------- stage 1 (R16 shape, wave-contiguous Hermitian tiles) ---------
    {
        const bool act = t < 144;              // waves 0-1 dense, w2 1/4, w3 off
        const int bg = t % 9;                  // b-group 0..8  (b0 = 0..32)
        const int dp = t / 9;                  // d-pair 0..15  (for t < 144)
        const int b0 = bg * 4;
        const int d0 = dp * 2;
        float Ter[2][4], Tei[2][4], Tor[2][4], Toi[2][4];
        #pragma unroll
        for (int j = 0; j < 2; j++)
            #pragma unroll
            for (int i = 0; i < 4; i++) {
                Ter[j][i] = 0.0f; Tei[j][i] = 0.0f;
                Tor[j][i] = 0.0f; Toi[j][i] = 0.0f;
            }
        float rr[2], ri[2], wr[2], wi[2];
        if (act) {
            #pragma unroll
            for (int j = 0; j < 2; j++) {
                float s, c; fsincos((TWO_PI / 32.0f) * (float)(d0 + j), &s, &c);
                wr[j] = c; wi[j] = s; rr[j] = 1.0f; ri[j] = 0.0f;
            }
            // explicit prefetch double-buffer over a2 (R16 verbatim)
            float4 vre = *(const float4*)&EHr[b0];
            float4 vie = *(const float4*)&EHi[b0];
            float4 vro = *(const float4*)&EHr[64 + b0];
            float4 vio = *(const float4*)&EHi[64 + b0];
            #pragma unroll 4
            for (int a2 = 0; a2 < 32; a2++) {
                const float4 cre = vre, cie = vie, cro = vro, cio = vio;
                if (a2 < 31) {
                    const int nb = 128 * (a2 + 1) + b0;
                    vre = *(const float4*)&EHr[nb];
                    vie = *(const float4*)&EHi[nb];
                    vro = *(const float4*)&EHr[nb + 64];
                    vio = *(const float4*)&EHi[nb + 64];
                }
                const float ere[4] = {cre.x, cre.y, cre.z, cre.w};
                const float eie[4] = {cie.x, cie.y, cie.z, cie.w};
                const float ero[4] = {cro.x, cro.y, cro.z, cro.w};
                const float eio[4] = {cio.x, cio.y, cio.z, cio.w};
                #pragma unroll
                for (int j = 0; j < 2; j++) {
                    #pragma unroll
                    for (int i = 0; i < 4; i++) {
                        Ter[j][i] += ere[i] * rr[j] - eie[i] * ri[j];
                        Tei[j][i] += ere[i] * ri[j] + eie[i] * rr[j];
                        Tor[j][i] += ero[i] * rr[j] - eio[i] * ri[j];
                        Toi[j][i] += ero[i] * ri[j] + eio[i] * rr[j];
                    }
                    const float nr = rr[j] * wr[j] - ri[j] * wi[j];
                    const float ni = rr[j] * wi[j] + ri[j] * wr[j];
                    rr[j] = nr; ri[j] = ni;
                }
            }
        }
        __syncthreads();   // uniform barrier: ALL E reads done before G' store

        if (act) {
            // radix-2 butterfly + bd/4096 twiddle + store (b <= 32 only)
            float os[2], oc[2];
            #pragma unroll
            for (int j = 0; j < 2; j++)
                fsincos((TWO_PI / 64.0f) * (float)(d0 + j), &os[j], &oc[j]);
            #pragma unroll
            for (int i = 0; i < 4; i++) {
                const int b = b0 + i;
                if (b > 32) continue;
                float gpr[2], gpi[2], gmr[2], gmi[2];
                #pragma unroll
                for (int j = 0; j < 2; j++) {
                    const int d = d0 + j;
                    const float ur = oc[j] * Tor[j][i] - os[j] * Toi[j][i];
                    const float ui = oc[j] * Toi[j][i] + os[j] * Tor[j][i];
                    const float pr = Ter[j][i] + ur, pi = Tei[j][i] + ui;
                    const float mr = Ter[j][i] - ur, mi = Tei[j][i] - ui;
                    float s, c;
                    fsincos((TWO_PI / 4096.0f) * (float)(b * d), &s, &c);
                    gpr[j] = pr * c - pi * s; gpi[j] = pr * s + pi * c;
                    fsincos((TWO_PI / 4096.0f) * (float)(b * (d + 32)), &s, &c);
                    gmr[j] = mr * c - mi * s; gmi[j] = mr * s + mi * c;
                }
                *(float2*)&Gr[b * GS + d0]      = make_float2(gpr[0], gpr[1]);
                *(float2*)&Gi[b * GS + d0]      = make_float2(gpi[0], gpi[1]);
                *(float2*)&Gr[b * GS + d0 + 32] = make_float2(gmr[0], gmr[1]);
                *(float2*)&Gi[b * GS + d0 + 32] = make_float2(gmi[0], gmi[1]);
            }
        }
    }
    __syncthreads();

    // ---------------- stage 2 (R17 rolled loop, 4 groups = b 0..31) -------
    float hv[4][2];
    int   dl_, cg_;
    {
        const int dl = (t & 31) * 2;
        const int cg = t >> 5;                     // 0..7
        dl_ = dl; cg_ = cg;
        float swi_, swr_; fsincos((TWO_PI / 64.0f) * (float)cg, &swi_, &swr_);
        const float swr = swr_, swi = swi_;        // step e^{2pi i cg/64}
        float rr = 1.0f, ri = 0.0f;
        float acc00 = 0, acc01 = 0, acc10 = 0, acc11 = 0;
        float acc20 = 0, acc21 = 0, acc30 = 0, acc31 = 0;
        int bb = 0;

#define S2C 0.70710678118654752f
#define STEP2(f8r, f8i, f16r, f16i, f24r, f24i)                                \
        {                                                                      \
            const float2 g_r = *(const float2*)&Gr[bb * GS + dl];              \
            const float2 g_i = *(const float2*)&Gi[bb * GS + dl];              \
            acc00 += g_r.x * rr - g_i.x * ri;                                  \
            acc01 += g_r.y * rr - g_i.y * ri;                                  \
            { const float tr = rr*(f8r) - ri*(f8i), ti = rr*(f8i) + ri*(f8r);  \
              acc10 += g_r.x * tr - g_i.x * ti;                                \
              acc11 += g_r.y * tr - g_i.y * ti; }                              \
            { const float tr = rr*(f16r) - ri*(f16i), ti = rr*(f16i) + ri*(f16r); \
              acc20 += g_r.x * tr - g_i.x * ti;                                \
              acc21 += g_r.y * tr - g_i.y * ti; }                              \
            { const float tr = rr*(f24r) - ri*(f24i), ti = rr*(f24i) + ri*(f24r); \
              acc30 += g_r.x * tr - g_i.x * ti;                                \
              acc31 += g_r.y * tr - g_i.y * ti; }                              \
            { const float nr = rr * swr - ri * swi;                            \
              const float ni = rr * swi + ri * swr;                            \
              rr = nr; ri = ni; }                                              \
            bb++;                                                              \
        }

        #pragma unroll 1
        for (int grp = 0; grp < 4; grp++) {        // b = 0..31 (rolled!)
            STEP2( 1.0f, 0.0f,   1.0f, 0.0f,   1.0f, 0.0f)
            STEP2( S2C,  S2C,    0.0f, 1.0f,  -S2C,  S2C)
            STEP2( 0.0f, 1.0f,  -1.0f, 0.0f,   0.0f,-1.0f)
            STEP2(-S2C,  S2C,    0.0f,-1.0f,   S2C,  S2C)
            STEP2(-1.0f, 0.0f,   1.0f, 0.0f,  -1.0f, 0.0f)
            STEP2(-S2C, -S2C,    0.0f, 1.0f,   S2C, -S2C)
            STEP2( 0.0f,-1.0f,  -1.0f, 0.0f,   0.0f, 1.0f)
            STEP2( S2C, -S2C,    0.0f,-1.0f,  -S2C, -S2C)
        }
#undef STEP2

        // Hermitian fixup: true sum = 2*acc - g0 + (-1)^cg * g32, /4096
        const float g0a  = Gr[dl],           g0b  = Gr[dl + 1];
        const float g32a = Gr[32 * GS + dl], g32b = Gr[32 * GS + dl + 1];
        const float sgn  = (cg & 1) ? -1.0f : 1.0f;   // (-1)^{cg+8v} = (-1)^cg
        const float sc = 1.0f / 4096.0f;
        hv[0][0] = (2.0f * acc00 - g0a + sgn * g32a) * sc;
        hv[0][1] = (2.0f * acc01 - g0b + sgn * g32b) * sc;
        hv[1][0] = (2.0f * acc10 - g0a + sgn * g32a) * sc;
        hv[1][1] = (2.0f * acc11 - g0b + sgn * g32b) * sc;
        hv[2][0] = (2.0f * acc20 - g0a + sgn * g32a) * sc;
        hv[2][1] = (2.0f * acc21 - g0b + sgn * g32b) * sc;
        hv[3][0] = (2.0f * acc30 - g0a + sgn * g32a) * sc;
        hv[3][1] = (2.0f * acc31 - g0b + sgn * g32b) * sc;
    }
    __syncthreads();   // all G reads done; U is free

    // ---------------- h -> LDS ----------------
    #pragma unroll
    for (int v = 0; v < 4; v++) {
        const int c = cg_ + 8 * v;
        const int n = 64 * c + dl_;
        if (n < IR_LEN)     hU[n]     = hv[v][0];
        if (n + 1 < IR_LEN) hU[n + 1] = hv[v][1];
    }
    __syncthreads();

    // ---------------- FIR: z[o], o in [0,160) ----------------
    if (t < 240) {
        const int o0 = (t % 20) * 8;
        const int kc = t / 20;                 // 0..11
        const int kb = kc * 168;
        const int ns = (kc == 11) ? 38 : 42;   // 11*168=1848, +152 = 2000
        float s0[8] = {0,0,0,0,0,0,0,0};
        int Bo = o0 + 1996 - kb;               // mult of 4, >= 0
        float4 w1 = *(const float4*)&xws[XPHYS(Bo + 4)];
        float4 w2 = *(const float4*)&xws[XPHYS(Bo + 8)];
        for (int s = 0; s < ns; s++) {
            const float4 w0 = *(const float4*)&xws[XPHYS(Bo)];
            const float4 ha = *(const float4*)&hU[kb + 4 * s];
            const float wv[12] = {w0.x, w0.y, w0.z, w0.w,
                                  w1.x, w1.y, w1.z, w1.w,
                                  w2.x, w2.y, w2.z, w2.w};
            const float hav[4] = {ha.x, ha.y, ha.z, ha.w};
            #pragma unroll
            for (int jo = 0; jo < 8; jo++) {
                #pragma unroll
                for (int jk = 0; jk < 4; jk++) {
                    s0[jo] += hav[jk] * wv[3 + jo - jk];
                }
            }
            w2 = w1; w1 = w0; Bo -= 4;
        }
        const int rb = kc * 168 + o0;
        *(float4*)&red[rb]     = make_float4(s0[0], s0[1], s0[2], s0[3]);
        *(float4*)&red[rb + 4] = make_float4(s0[4], s0[5], s0[6], s0[7]);
    }
    __syncthreads();

    // ---------------- epilogue: tent-weighted atomic scatter ----------------
    if (t < 160) {
        float z = 0.0f;
        #pragma unroll
        for (int kc = 0; kc < 12; kc++) z += red[kc * 168 + t];
        const int o = t;
        const int tout = t0 - PFRAME + o;
        float wgt = (o < PFRAME) ? (float)o * (1.0f / PFRAME)
                                 : (float)(160 - o) * (1.0f / PFRAME);
        if (frame == NFRAMES - 1 && o >= PFRAME) wgt = 1.0f;  // clamped h_next
        if (tout >= 0) {                       // frame 0 has no previous frame
            atomicAdd(&y[batch * T_TOTAL + tout], wgt * z);
        }
    }
}

extern "C" void kernel_launch(void* const* d_in, const int* in_sizes, int n_in,
                              void* d_out, int out_size, void* d_ws, size_t ws_size,
                              hipStream_t stream) {
    const float* x  = (const float*)d_in[0];   // (2, 24000)
    const float* mc = (const float*)d_in[1];   // (2, 300, 25)
    float* y = (float*)d_out;                  // (2, 24000)

    hipMemsetAsync(y, 0, (size_t)out_size * sizeof(float), stream);
    minphase_fir_fused<<<NROWS, 256, 0, stream>>>(mc, x, y);
}